// Round 9
// baseline (231.487 us; speedup 1.0000x reference)
//
#include <hip/hip_runtime.h>

#define N_NODES 50000
#define D_NB 16
#define IN_DIM 256
#define OUT_DIM 128
#define K_HEADS 4
#define SLOPE 0.01f
#define NSLICE 16       // slice s = k*4 + cb; 32 cols each
#define SLICE_COLS 32
#define NSLOT 256       // attn blocks per XCD-group

typedef __attribute__((ext_vector_type(8))) short short8;
typedef __attribute__((ext_vector_type(4))) float f32x4;
typedef __attribute__((ext_vector_type(2))) float f32x2;

static __device__ __forceinline__ unsigned short f2bf(float f) {
    unsigned u = __float_as_uint(f);
    unsigned r = u + 0x7fffu + ((u >> 16) & 1u);   // RNE
    return (unsigned short)(r >> 16);
}
static __device__ __forceinline__ float bf2f(unsigned short b) {
    return __uint_as_float(((unsigned)b) << 16);
}

// ---------------- Kernel 0: W (f32) -> Wb (bf16), same [K][OUT][IN] layout ----------------
__global__ void wb_kernel(const float* __restrict__ W, unsigned short* __restrict__ Wb) {
    int id = blockIdx.x * blockDim.x + threadIdx.x;
    if (id < K_HEADS * OUT_DIM * IN_DIM) Wb[id] = f2bf(W[id]);
}

// ---------------- Kernel 1: MFMA GEMM, 64 rows/block, 16 x 16KB double-buffered stages ----------
// (unchanged from round 7 — passed, ~45 µs)
__global__ __launch_bounds__(256) void gemm_kernel(
    const float* __restrict__ X, const unsigned short* __restrict__ Wb,
    const float* __restrict__ a,
    unsigned short* __restrict__ Whb2, float* __restrict__ e_nb, float* __restrict__ e_self)
{
    __shared__ unsigned short Wlds[2][SLICE_COLS * IN_DIM];   // 2 x 16 KB

    const int t = threadIdx.x;
    const int lane = t & 63;
    const int w = t >> 6;
    const int lrow = lane & 15;
    const int lk = lane >> 4;
    const int m0 = blockIdx.x * 64 + w * 16;

    const int arow = m0 + lrow;
    const bool avalid = arow < N_NODES;

    const float* Xr = X + (size_t)arow * IN_DIM + lk * 8;
    short8 af[8];
    #pragma unroll
    for (int kk = 0; kk < 8; ++kk) {
        short8 s;
        if (avalid) {
            float4 x0 = *(const float4*)(Xr + kk * 32);
            float4 x1 = *(const float4*)(Xr + kk * 32 + 4);
            s[0] = (short)f2bf(x0.x); s[1] = (short)f2bf(x0.y);
            s[2] = (short)f2bf(x0.z); s[3] = (short)f2bf(x0.w);
            s[4] = (short)f2bf(x1.x); s[5] = (short)f2bf(x1.y);
            s[6] = (short)f2bf(x1.z); s[7] = (short)f2bf(x1.w);
        } else {
            s = short8{0, 0, 0, 0, 0, 0, 0, 0};
        }
        af[kk] = s;
    }

    auto STAGE = [&](int st, int buf) {
        const unsigned short* WbS = Wb + (size_t)st * SLICE_COLS * IN_DIM;
        #pragma unroll
        for (int i = 0; i < 4; ++i) {
            const int c = i * 256 + t;
            const int r = c >> 5;
            const int p = c & 31;
            const int cu = p ^ (r & 7);
            const unsigned short* gsrc = WbS + r * IN_DIM + cu * 8;
            unsigned short* ldst = &Wlds[buf][c * 8];
            __builtin_amdgcn_global_load_lds(
                (const __attribute__((address_space(1))) void*)gsrc,
                (__attribute__((address_space(3))) void*)ldst, 16, 0, 0);
        }
    };

    float pnb = 0.f, psf = 0.f;
    STAGE(0, 0);
    __syncthreads();

    for (int st = 0; st < NSLICE; ++st) {
        const int buf = st & 1;
        if (st + 1 < NSLICE) STAGE(st + 1, buf ^ 1);

        f32x4 acc[2] = {};
        #pragma unroll
        for (int kk = 0; kk < 8; ++kk) {
            #pragma unroll
            for (int nt = 0; nt < 2; ++nt) {
                const int row = nt * 16 + lrow;
                const int pos = (kk * 4 + lk) ^ (row & 7);
                const short8 bf = *(const short8*)(&Wlds[buf][row * IN_DIM + pos * 8]);
                acc[nt] = __builtin_amdgcn_mfma_f32_16x16x32_bf16(bf, af[kk], acc[nt], 0, 0, 0);
            }
        }

        const int k = st >> 2, cb = st & 3;
        #pragma unroll
        for (int nt = 0; nt < 2; ++nt) {
            const float4 anb = *(const float4*)(a + k * 2 * OUT_DIM + cb * 32 + nt * 16 + lk * 4);
            const float4 asf = *(const float4*)(a + k * 2 * OUT_DIM + OUT_DIM + cb * 32 + nt * 16 + lk * 4);
            pnb += acc[nt][0] * anb.x + acc[nt][1] * anb.y
                 + acc[nt][2] * anb.z + acc[nt][3] * anb.w;
            psf += acc[nt][0] * asf.x + acc[nt][1] * asf.y
                 + acc[nt][2] * asf.z + acc[nt][3] * asf.w;
            if (avalid) {
                uint2 pk;
                pk.x = (unsigned)f2bf(acc[nt][0]) | ((unsigned)f2bf(acc[nt][1]) << 16);
                pk.y = (unsigned)f2bf(acc[nt][2]) | ((unsigned)f2bf(acc[nt][3]) << 16);
                *(uint2*)(Whb2 + ((size_t)st * N_NODES + arow) * SLICE_COLS + nt * 16 + lk * 4) = pk;
            }
        }
        if ((st & 3) == 3) {
            pnb += __shfl_xor(pnb, 16); pnb += __shfl_xor(pnb, 32);
            psf += __shfl_xor(psf, 16); psf += __shfl_xor(psf, 32);
            if (avalid && lane < 16) {
                e_nb[(size_t)arow * K_HEADS + k] = pnb;
                e_self[(size_t)arow * K_HEADS + k] = psf;
            }
            pnb = 0.f; psf = 0.f;
        }
        __syncthreads();
    }
}

// ---------------- Kernel 2: XCD-sliced gather, ONE 3.2MB slice per XCD per pass ----------------
// Pass p: XCD x (blockIdx&7) owns slice s = x + 8p (32 cols, 3.2 MB <= 4 MB L2).
// Cached working set per XCD: slice (3.2 MB) + e_nb (0.8 MB) = 4.0 MB.
// nidx / e_self loads and out stores are non-temporal (no L2 pollution).
// 16 lanes per node: lane d = softmax slot AND col-pair {2d,2d+1} of the 32-col slice.
__global__ __launch_bounds__(256) void attn_kernel(
    const int* __restrict__ nidx, const unsigned short* __restrict__ Whb2,
    const float* __restrict__ e_nb, const float* __restrict__ e_self,
    float* __restrict__ out)
{
    const int xcd = blockIdx.x & 7;
    const int slot = blockIdx.x >> 3;       // 0..NSLOT-1
    const int w = threadIdx.x >> 6;
    const int lane = threadIdx.x & 63;
    const int nl = lane >> 4;               // node within wave (0..3)
    const int d = lane & 15;

    #pragma unroll
    for (int p = 0; p < 2; ++p) {
        const int s = xcd + p * 8;
        const int k = s >> 2;               // head
        const int cb = s & 3;               // col-block
        const unsigned short* S = Whb2 + (size_t)s * N_NODES * SLICE_COLS;

        for (int i = slot; i < N_NODES / 16; i += NSLOT) {
            const int n = i * 16 + w * 4 + nl;

            const int nbr = __builtin_nontemporal_load(nidx + (size_t)n * D_NB + d);
            const float es = __builtin_nontemporal_load(e_self + (size_t)n * K_HEADS + k);
            const float x = e_nb[(size_t)nbr * K_HEADS + k] + es;
            const float v = x > 0.f ? x : SLOPE * x;
            float m = v;
            #pragma unroll
            for (int sh = 8; sh >= 1; sh >>= 1) m = fmaxf(m, __shfl_xor(m, sh, 16));
            const float pz = __expf(v - m);
            float sum = pz;
            #pragma unroll
            for (int sh = 8; sh >= 1; sh >>= 1) sum += __shfl_xor(sum, sh, 16);
            const float alpha = pz / sum;

            float a0 = 0.f, a1 = 0.f;
            #pragma unroll
            for (int dd = 0; dd < D_NB; ++dd) {
                const int src = (lane & 48) | dd;
                const float ad = __shfl(alpha, src);
                const int nd = __shfl(nbr, src);
                const unsigned u = *(const unsigned*)(S + (size_t)nd * SLICE_COLS + d * 2);
                a0 += ad * bf2f((unsigned short)(u & 0xffffu));
                a1 += ad * bf2f((unsigned short)(u >> 16));
            }
            f32x2* op = (f32x2*)(out + (size_t)n * (K_HEADS * OUT_DIM) + k * OUT_DIM
                                 + cb * SLICE_COLS + d * 2);
            __builtin_nontemporal_store(f32x2{a0, a1}, op);
        }
        __syncthreads();   // keep the two passes roughly phase-separated per block
    }
}

// ---------------- launch ----------------
extern "C" void kernel_launch(void* const* d_in, const int* in_sizes, int n_in,
                              void* d_out, int out_size, void* d_ws, size_t ws_size,
                              hipStream_t stream) {
    const float* X = (const float*)d_in[0];
    const float* W = (const float*)d_in[1];
    const float* a = (const float*)d_in[2];
    const int* nidx = (const int*)d_in[3];
    float* out = (float*)d_out;

    char* p = (char*)d_ws;
    unsigned short* Wb = (unsigned short*)p;      p += (size_t)K_HEADS * OUT_DIM * IN_DIM * 2;
    unsigned short* Whb2 = (unsigned short*)p;    p += (size_t)NSLICE * N_NODES * SLICE_COLS * 2;
    float* enb = (float*)p;                       p += (size_t)N_NODES * K_HEADS * 4;
    float* eself = (float*)p;

    hipLaunchKernelGGL(wb_kernel,
        dim3((K_HEADS * OUT_DIM * IN_DIM + 255) / 256), dim3(256), 0, stream, W, Wb);

    hipLaunchKernelGGL(gemm_kernel,
        dim3((N_NODES + 63) / 64), dim3(256), 0, stream, X, Wb, a, Whb2, enb, eself);

    hipLaunchKernelGGL(attn_kernel,
        dim3(8 * NSLOT), dim3(256), 0, stream, nidx, Whb2, enb, eself, out);
}